// Round 16
// baseline (63.254 us; speedup 1.0000x reference)
//
#include <hip/hip_runtime.h>
#include <stdint.h>

// VectorQuantizer: x[32,64,64,64] NCHW fp32, W[512,64] fp32.
// argmin_k ||x - w_k||^2 ; out = W[argmin] in NCHW.
//
// v16 = v15 + T14 2-group pipeline: 512-thr blocks own 256 tokens as 2x128
// double-buffered groups; group g+1's global loads are issued before group g's
// sweep (HBM hides under compute); pack/write(g+1) overlaps resolve/refine/
// store(g). Wave-local staging (wave stages its own 16 tokens) so margin
// needs only shfl. Code-slice ownership sweep: wave w holds A-frags of codes
// w*64..+63 in 32 VGPRs; single-pass max+mask; margin 2^-7*||x||*Wmax+0.02;
// singleton exact; multi -> worklist -> whole-wave fp64 refine.

typedef short short8 __attribute__((ext_vector_type(8)));
typedef float f32x4 __attribute__((ext_vector_type(4)));
typedef unsigned u32x4 __attribute__((ext_vector_type(4)));

#define HW_ 4096

__device__ __forceinline__ unsigned short f2bf(float f) {
    unsigned u = __float_as_uint(f);
    u += 0x7fff + ((u >> 16) & 1);   // RNE to bf16
    return (unsigned short)(u >> 16);
}

// Image: ushort idx(k,d) = (d>>3)*4096 + k*8 + (d&7)   [8 octet-planes]
__global__ __launch_bounds__(64) void vq_prep(const float* __restrict__ W,
                                              unsigned short* __restrict__ Wb,
                                              float* __restrict__ nh,
                                              int* __restrict__ wmax2i) {
    const int k = blockIdx.x, l = threadIdx.x;
    float v = W[k * 64 + l];
    Wb[(l >> 3) * 4096 + k * 8 + (l & 7)] = f2bf(v);
    float s = v * v;
    #pragma unroll
    for (int off = 1; off < 64; off <<= 1) s += __shfl_xor(s, off);
    if (l == 0) {
        nh[k] = -0.5f * s;
        atomicMax(wmax2i, __float_as_int(s));
    }
}

__global__ __launch_bounds__(512, 2) void vq_main(const float* __restrict__ x,
                                                  const float* __restrict__ W,
                                                  const unsigned short* __restrict__ Wb,
                                                  const float* __restrict__ nh,
                                                  const int* __restrict__ wmax2i,
                                                  float* __restrict__ out) {
    __shared__ unsigned short xb[2][8192];          // 2 x 16 KiB swizzled tokens
    __shared__ float wavemax[2][8][128];            // 8 KiB
    __shared__ unsigned long long cmask[2][8][128]; // 16 KiB
    __shared__ float marginArr[2][128];             // 1 KiB
    __shared__ float thrArr[2][128];                // 1 KiB
    __shared__ int bkArr[2][128];                   // 1 KiB
    __shared__ int wlist[2][128];                   // 1 KiB
    __shared__ int wcnt[2];

    const int tid = threadIdx.x;
    const int bid = blockIdx.x;
    const int b = bid >> 4;                 // batch 0..31
    const int p0 = (bid & 15) << 8;         // 256-token block base
    const int l = tid & 63;
    const int wv = tid >> 6;                // wave 0..7 owns codes wv*64..+63

    if (tid < 2) wcnt[tid] = 0;

    // ---- this wave's A-fragments (4 tiles) + nh C-inits, in registers ----
    short8 a0_0, a0_1, a0_2, a0_3, a1_0, a1_1, a1_2, a1_3;
    f32x4 nhv0, nhv1, nhv2, nhv3;
    {
        const unsigned short* Ap = Wb + (l >> 4) * 4096 + ((wv * 4) * 16 + (l & 15)) * 8;
        const unsigned short* Aq = Ap + 4 * 4096;
        a0_0 = *(const short8*)(Ap);        a1_0 = *(const short8*)(Aq);
        a0_1 = *(const short8*)(Ap + 128);  a1_1 = *(const short8*)(Aq + 128);
        a0_2 = *(const short8*)(Ap + 256);  a1_2 = *(const short8*)(Aq + 256);
        a0_3 = *(const short8*)(Ap + 384);  a1_3 = *(const short8*)(Aq + 384);
        const float* np = nh + (wv * 4) * 16 + (l >> 4) * 4;
        nhv0 = *(const f32x4*)(np);
        nhv1 = *(const f32x4*)(np + 16);
        nhv2 = *(const f32x4*)(np + 32);
        nhv3 = *(const f32x4*)(np + 48);
    }
    const float wm2 = __int_as_float(*wmax2i);

    // wave-local staging identity: lane stages token wv*16+(l&15), dims sq*16..+16
    const int stok = wv * 16 + (l & 15);
    const int sq = l >> 4;
    float sv[16];

#define STAGE_ISSUE(G) {                                                             \
        const float* xp = x + (size_t)(b * 64 + sq * 16) * HW_ + p0 + (G) * 128 + stok; \
        _Pragma("unroll")                                                            \
        for (int e = 0; e < 16; ++e) sv[e] = xp[(size_t)e * HW_];                    \
    }

#define STAGE_WRITE(G) {                                                             \
        float xsq = 0.f;                                                             \
        u32x4 pk0, pk1;                                                              \
        _Pragma("unroll")                                                            \
        for (int p = 0; p < 4; ++p) {                                                \
            xsq += sv[2*p]*sv[2*p] + sv[2*p+1]*sv[2*p+1]                             \
                 + sv[8+2*p]*sv[8+2*p] + sv[9+2*p]*sv[9+2*p];                        \
            pk0[p] = (unsigned)f2bf(sv[2*p])   | ((unsigned)f2bf(sv[2*p+1]) << 16);  \
            pk1[p] = (unsigned)f2bf(sv[8+2*p]) | ((unsigned)f2bf(sv[9+2*p]) << 16);  \
        }                                                                            \
        xsq += __shfl_xor(xsq, 16);                                                  \
        xsq += __shfl_xor(xsq, 32);                                                  \
        const int s0 = (sq * 2) ^ (l & 7);                                           \
        const int s1 = (sq * 2 + 1) ^ (l & 7);                                       \
        *(u32x4*)((char*)xb[G] + stok * 128 + s0 * 16) = pk0;                        \
        *(u32x4*)((char*)xb[G] + stok * 128 + s1 * 16) = pk1;                        \
        if (sq == 0) marginArr[G][stok] = ldexpf(sqrtf(xsq * wm2), -7) + 0.02f;      \
    }

#define SWEEP(G) {                                                                   \
        const int off0 = (((l >> 4)    ) ^ (l & 7)) * 16;                            \
        const int off1 = (((l >> 4) + 4) ^ (l & 7)) * 16;                            \
        const char* xbB = (const char*)xb[G] + (l & 15) * 128;                       \
        const int rowbase = (l >> 4) * 4;                                            \
        _Pragma("unroll 1")                                                          \
        for (int g16 = 0; g16 < 8; ++g16) {                                          \
            const float marg = marginArr[G][g16 * 16 + (l & 15)];                    \
            short8 b0 = *(const short8*)(xbB + g16 * 2048 + off0);                   \
            short8 b1 = *(const short8*)(xbB + g16 * 2048 + off1);                   \
            f32x4 c0 = nhv0, c1 = nhv1, c2 = nhv2, c3 = nhv3;                        \
            c0 = __builtin_amdgcn_mfma_f32_16x16x32_bf16(a0_0, b0, c0, 0, 0, 0);     \
            c1 = __builtin_amdgcn_mfma_f32_16x16x32_bf16(a0_1, b0, c1, 0, 0, 0);     \
            c2 = __builtin_amdgcn_mfma_f32_16x16x32_bf16(a0_2, b0, c2, 0, 0, 0);     \
            c3 = __builtin_amdgcn_mfma_f32_16x16x32_bf16(a0_3, b0, c3, 0, 0, 0);     \
            c0 = __builtin_amdgcn_mfma_f32_16x16x32_bf16(a1_0, b1, c0, 0, 0, 0);     \
            c1 = __builtin_amdgcn_mfma_f32_16x16x32_bf16(a1_1, b1, c1, 0, 0, 0);     \
            c2 = __builtin_amdgcn_mfma_f32_16x16x32_bf16(a1_2, b1, c2, 0, 0, 0);     \
            c3 = __builtin_amdgcn_mfma_f32_16x16x32_bf16(a1_3, b1, c3, 0, 0, 0);     \
            float mm = fmaxf(fmaxf(fmaxf(c0[0], c0[1]), fmaxf(c0[2], c0[3])),        \
                             fmaxf(fmaxf(c1[0], c1[1]), fmaxf(c1[2], c1[3])));       \
            mm = fmaxf(mm, fmaxf(fmaxf(c2[0], c2[1]), fmaxf(c2[2], c2[3])));         \
            mm = fmaxf(mm, fmaxf(fmaxf(c3[0], c3[1]), fmaxf(c3[2], c3[3])));         \
            mm = fmaxf(mm, __shfl_xor(mm, 16));                                      \
            mm = fmaxf(mm, __shfl_xor(mm, 32));                                      \
            const float thr = mm - marg;                                             \
            unsigned long long msk = 0;                                              \
            unsigned b4 = 0;                                                         \
            _Pragma("unroll")                                                        \
            for (int r = 0; r < 4; ++r) b4 |= (c0[r] >= thr ? 1u : 0u) << r;         \
            msk |= (unsigned long long)b4 << (0 * 16 + rowbase);                     \
            b4 = 0;                                                                  \
            _Pragma("unroll")                                                        \
            for (int r = 0; r < 4; ++r) b4 |= (c1[r] >= thr ? 1u : 0u) << r;         \
            msk |= (unsigned long long)b4 << (1 * 16 + rowbase);                     \
            b4 = 0;                                                                  \
            _Pragma("unroll")                                                        \
            for (int r = 0; r < 4; ++r) b4 |= (c2[r] >= thr ? 1u : 0u) << r;         \
            msk |= (unsigned long long)b4 << (2 * 16 + rowbase);                     \
            b4 = 0;                                                                  \
            _Pragma("unroll")                                                        \
            for (int r = 0; r < 4; ++r) b4 |= (c3[r] >= thr ? 1u : 0u) << r;         \
            msk |= (unsigned long long)b4 << (3 * 16 + rowbase);                     \
            msk |= __shfl_xor(msk, 16);                                              \
            msk |= __shfl_xor(msk, 32);                                              \
            if (l < 16) {                                                            \
                wavemax[G][wv][g16 * 16 + l] = mm;                                   \
                cmask[G][wv][g16 * 16 + l] = msk;                                    \
            }                                                                        \
        }                                                                            \
    }

#define RESOLVE_PART1(G)                                                             \
    if (tid < 128) {                                                                 \
        const int tok = tid;                                                         \
        float gm = wavemax[G][0][tok];                                               \
        _Pragma("unroll")                                                            \
        for (int w = 1; w < 8; ++w) gm = fmaxf(gm, wavemax[G][w][tok]);              \
        const float thr = gm - marginArr[G][tok];                                    \
        thrArr[G][tok] = thr;                                                        \
        int cnt = 0;                                                                 \
        int bk = -1;                                                                 \
        _Pragma("unroll")                                                            \
        for (int w = 0; w < 8; ++w) {                                                \
            if (wavemax[G][w][tok] >= thr) {                                         \
                unsigned long long mmm = cmask[G][w][tok];                           \
                cnt += __popcll(mmm);                                                \
                if (mmm) bk = w * 64 + __builtin_ctzll(mmm);                         \
            }                                                                        \
        }                                                                            \
        if (cnt == 1) bkArr[G][tok] = bk;                                            \
        else wlist[G][atomicAdd(&wcnt[G], 1)] = tok;                                 \
    }

#define RESOLVE_PART2(G) {                                                           \
        const int nW = wcnt[G];                                                      \
        for (int i = wv; i < nW; i += 8) {                                           \
            const int tok = wlist[G][i];                                             \
            const float thr = thrArr[G][tok];                                        \
            const double xl = (double)x[(size_t)(b * 64 + l) * HW_ + p0 + (G) * 128 + tok]; \
            double bd = 1.0e308;                                                     \
            int bk = 0x7fffffff;                                                     \
            _Pragma("unroll 1")                                                      \
            for (int w = 0; w < 8; ++w) {                                            \
                if (wavemax[G][w][tok] < thr) continue;                              \
                unsigned long long mm = cmask[G][w][tok];                            \
                while (mm) {                                                         \
                    const int bit = __builtin_ctzll(mm); mm &= mm - 1;               \
                    const int k = w * 64 + bit;                                      \
                    double dl = xl - (double)W[k * 64 + l];                          \
                    double p = dl * dl;                                              \
                    _Pragma("unroll")                                                \
                    for (int off = 1; off < 64; off <<= 1) p += __shfl_xor(p, off);  \
                    if (p < bd) { bd = p; bk = k; }                                  \
                }                                                                    \
            }                                                                        \
            if (l == 0) bkArr[G][tok] = bk;                                          \
        }                                                                            \
    }

#define EPILOGUE(G) {                                                                \
        const int pp = tid & 127;                                                    \
        const int dq = tid >> 7;                                                     \
        const int kk = bkArr[G][pp];                                                 \
        const float* wr = W + kk * 64 + dq * 16;                                     \
        float* ob = out + (size_t)b * 262144 + p0 + (G) * 128 + pp;                  \
        _Pragma("unroll")                                                            \
        for (int j = 0; j < 4; ++j) {                                                \
            f32x4 v = *(const f32x4*)(wr + j * 4);                                   \
            ob[(size_t)(dq * 16 + j * 4 + 0) * HW_] = v[0];                          \
            ob[(size_t)(dq * 16 + j * 4 + 1) * HW_] = v[1];                          \
            ob[(size_t)(dq * 16 + j * 4 + 2) * HW_] = v[2];                          \
            ob[(size_t)(dq * 16 + j * 4 + 3) * HW_] = v[3];                          \
        }                                                                            \
    }

    // ---- pipelined schedule ----
    STAGE_ISSUE(0)
    STAGE_WRITE(0)
    __syncthreads();                 // xb[0], marginArr[0] ready

    STAGE_ISSUE(1)                   // HBM for group 1 in flight under sweep 0
    SWEEP(0)
    __syncthreads();                 // wavemax/cmask[0] ready

    STAGE_WRITE(1)                   // drain group-1 loads, write xb[1]
    RESOLVE_PART1(0)
    __syncthreads();                 // wlist[0] + xb[1]/marginArr[1] ready
    RESOLVE_PART2(0)
    __syncthreads();                 // bkArr[0] ready
    EPILOGUE(0)

    SWEEP(1)
    __syncthreads();                 // wavemax/cmask[1] ready
    RESOLVE_PART1(1)
    __syncthreads();
    RESOLVE_PART2(1)
    __syncthreads();
    EPILOGUE(1)

#undef STAGE_ISSUE
#undef STAGE_WRITE
#undef SWEEP
#undef RESOLVE_PART1
#undef RESOLVE_PART2
#undef EPILOGUE
}

extern "C" void kernel_launch(void* const* d_in, const int* in_sizes, int n_in,
                              void* d_out, int out_size, void* d_ws, size_t ws_size,
                              hipStream_t stream) {
    const float* x = (const float*)d_in[0];
    const float* W = (const float*)d_in[1];
    unsigned short* Wb = (unsigned short*)d_ws;              // 64 KiB image
    float* nh = (float*)((char*)d_ws + 65536);               // 512 f32
    int* wmax2i = (int*)((char*)d_ws + 65536 + 2048);        // 1 int (float bits)
    hipMemsetAsync(wmax2i, 0, 4, stream);
    vq_prep<<<512, 64, 0, stream>>>(W, Wb, nh, wmax2i);
    vq_main<<<512, 512, 0, stream>>>(x, W, Wb, nh, wmax2i, (float*)d_out);
}

// Round 17
// 63.082 us; speedup vs baseline: 1.0027x; 1.0027x over previous
//
#include <hip/hip_runtime.h>
#include <stdint.h>

// VectorQuantizer: x[32,64,64,64] NCHW fp32, W[512,64] fp32.
// argmin_k ||x - w_k||^2 ; out = W[argmin] in NCHW.
//
// v17 = v15 + pair-parallel fp64 refine: resolution flattens all (tok,cand)
// pairs into an LDS list; 512 threads each compute one pair's exact fp64
// distance (serial 64-FMA chain, x column from L3, W row from L2) and fold
// into bestKey[tok] via 64-bit LDS atomicMin on (dist_bits & ~1023) | k
// (first-index tie semantics). wmax^2 reduced in-block from nh (no memset).
// Sweep: code-slice ownership, single-pass max+mask, margin
// 2^-7*||x||*Wmax+0.02 (certified superset), swizzled bf16 token LDS.

typedef short short8 __attribute__((ext_vector_type(8)));
typedef float f32x4 __attribute__((ext_vector_type(4)));
typedef unsigned u32x4 __attribute__((ext_vector_type(4)));

#define HW_ 4096

__device__ __forceinline__ unsigned short f2bf(float f) {
    unsigned u = __float_as_uint(f);
    u += 0x7fff + ((u >> 16) & 1);   // RNE to bf16
    return (unsigned short)(u >> 16);
}

// Image: ushort idx(k,d) = (d>>3)*4096 + k*8 + (d&7)   [8 octet-planes]
__global__ __launch_bounds__(64) void vq_prep(const float* __restrict__ W,
                                              unsigned short* __restrict__ Wb,
                                              float* __restrict__ nh) {
    const int k = blockIdx.x, l = threadIdx.x;
    float v = W[k * 64 + l];
    Wb[(l >> 3) * 4096 + k * 8 + (l & 7)] = f2bf(v);
    float s = v * v;
    #pragma unroll
    for (int off = 1; off < 64; off <<= 1) s += __shfl_xor(s, off);
    if (l == 0) nh[k] = -0.5f * s;
}

__global__ __launch_bounds__(512, 4) void vq_main(const float* __restrict__ x,
                                                  const float* __restrict__ W,
                                                  const unsigned short* __restrict__ Wb,
                                                  const float* __restrict__ nh,
                                                  float* __restrict__ out) {
    __shared__ unsigned short xb[128 * 64];        // 16 KiB swizzled bf16 tokens
    __shared__ float wavemax[8][128];              // 4 KiB
    __shared__ unsigned long long cmask[8][128];   // 8 KiB
    __shared__ float xsqpart[4][128];              // 2 KiB
    __shared__ float marginArr[128];               // 0.5 KiB
    __shared__ int bkArr[128];                     // 0.5 KiB
    __shared__ unsigned pairs[1024];               // 4 KiB (tok<<16 | k)
    __shared__ unsigned long long bestKey[128];    // 1 KiB
    __shared__ float red8[8];
    __shared__ int pcnt;

    const int tid = threadIdx.x;
    const int bid = blockIdx.x;
    const int b = bid >> 5;                 // batch 0..31
    const int p0 = (bid & 31) << 7;         // 128-token spatial base
    const int l = tid & 63;
    const int wv = tid >> 6;                // wave 0..7 owns codes wv*64..+63

    if (tid == 0) pcnt = 0;
    if (tid < 128) bestKey[tid] = ~0ull;

    // ---- this wave's A-fragments (4 tiles) + nh C-inits, in registers ----
    short8 a0_0, a0_1, a0_2, a0_3, a1_0, a1_1, a1_2, a1_3;
    f32x4 nhv0, nhv1, nhv2, nhv3;
    {
        const unsigned short* Ap = Wb + (l >> 4) * 4096 + ((wv * 4) * 16 + (l & 15)) * 8;
        const unsigned short* Aq = Ap + 4 * 4096;
        a0_0 = *(const short8*)(Ap);        a1_0 = *(const short8*)(Aq);
        a0_1 = *(const short8*)(Ap + 128);  a1_1 = *(const short8*)(Aq + 128);
        a0_2 = *(const short8*)(Ap + 256);  a1_2 = *(const short8*)(Aq + 256);
        a0_3 = *(const short8*)(Ap + 384);  a1_3 = *(const short8*)(Aq + 384);
        const float* np = nh + (wv * 4) * 16 + (l >> 4) * 4;
        nhv0 = *(const f32x4*)(np);
        nhv1 = *(const f32x4*)(np + 16);
        nhv2 = *(const f32x4*)(np + 32);
        nhv3 = *(const f32x4*)(np + 48);
    }

    // ---- in-block wmax^2: wave w reduces nh[w*64..+63] ----
    {
        float s = -2.0f * nh[wv * 64 + l];
        #pragma unroll
        for (int off = 1; off < 64; off <<= 1) s = fmaxf(s, __shfl_xor(s, off));
        if (l == 0) red8[wv] = s;
    }

    // ---- stage 128 tokens into swizzled LDS; xsq partials ----
    {
        const int tok = tid & 127;
        const int q = tid >> 7;              // dim quarter 0..3
        const float* xp = x + (size_t)(b * 64 + q * 16) * HW_ + p0 + tok;
        float xsq = 0.f;
        float v[16];
        #pragma unroll
        for (int e = 0; e < 16; ++e) {
            v[e] = xp[(size_t)e * HW_];
            xsq += v[e] * v[e];
        }
        u32x4 pk0, pk1;
        #pragma unroll
        for (int p = 0; p < 4; ++p) {
            pk0[p] = (unsigned)f2bf(v[2 * p])     | ((unsigned)f2bf(v[2 * p + 1]) << 16);
            pk1[p] = (unsigned)f2bf(v[8 + 2 * p]) | ((unsigned)f2bf(v[9 + 2 * p]) << 16);
        }
        const int s0 = (q * 2)     ^ (tok & 7);
        const int s1 = (q * 2 + 1) ^ (tok & 7);
        *(u32x4*)((char*)xb + tok * 128 + s0 * 16) = pk0;
        *(u32x4*)((char*)xb + tok * 128 + s1 * 16) = pk1;
        xsqpart[q][tok] = xsq;
    }
    __syncthreads();
    if (tid < 128) {
        float wm2 = red8[0];
        #pragma unroll
        for (int w = 1; w < 8; ++w) wm2 = fmaxf(wm2, red8[w]);
        const float xsq = xsqpart[0][tid] + xsqpart[1][tid] + xsqpart[2][tid] + xsqpart[3][tid];
        marginArr[tid] = ldexpf(sqrtf(xsq * wm2), -7) + 0.02f;   // 2E certified
    }
    __syncthreads();

    // lane-constant swizzled byte offsets (tok&7 == l&7 within every group)
    const int off0 = (((l >> 4)    ) ^ (l & 7)) * 16;
    const int off1 = (((l >> 4) + 4) ^ (l & 7)) * 16;
    const char* xbB = (const char*)xb + (l & 15) * 128;
    const int rowbase = (l >> 4) * 4;

    // ---- single sweep: scores -> wave max + candidate mask per token ----
    #pragma unroll 1
    for (int g16 = 0; g16 < 8; ++g16) {
        const float marg = marginArr[g16 * 16 + (l & 15)];
        short8 b0 = *(const short8*)(xbB + g16 * 2048 + off0);
        short8 b1 = *(const short8*)(xbB + g16 * 2048 + off1);
        f32x4 c0 = nhv0, c1 = nhv1, c2 = nhv2, c3 = nhv3;
        c0 = __builtin_amdgcn_mfma_f32_16x16x32_bf16(a0_0, b0, c0, 0, 0, 0);
        c1 = __builtin_amdgcn_mfma_f32_16x16x32_bf16(a0_1, b0, c1, 0, 0, 0);
        c2 = __builtin_amdgcn_mfma_f32_16x16x32_bf16(a0_2, b0, c2, 0, 0, 0);
        c3 = __builtin_amdgcn_mfma_f32_16x16x32_bf16(a0_3, b0, c3, 0, 0, 0);
        c0 = __builtin_amdgcn_mfma_f32_16x16x32_bf16(a1_0, b1, c0, 0, 0, 0);
        c1 = __builtin_amdgcn_mfma_f32_16x16x32_bf16(a1_1, b1, c1, 0, 0, 0);
        c2 = __builtin_amdgcn_mfma_f32_16x16x32_bf16(a1_2, b1, c2, 0, 0, 0);
        c3 = __builtin_amdgcn_mfma_f32_16x16x32_bf16(a1_3, b1, c3, 0, 0, 0);

        float mm = fmaxf(fmaxf(fmaxf(c0[0], c0[1]), fmaxf(c0[2], c0[3])),
                         fmaxf(fmaxf(c1[0], c1[1]), fmaxf(c1[2], c1[3])));
        mm = fmaxf(mm, fmaxf(fmaxf(c2[0], c2[1]), fmaxf(c2[2], c2[3])));
        mm = fmaxf(mm, fmaxf(fmaxf(c3[0], c3[1]), fmaxf(c3[2], c3[3])));
        mm = fmaxf(mm, __shfl_xor(mm, 16));
        mm = fmaxf(mm, __shfl_xor(mm, 32));
        const float thr = mm - marg;

        unsigned long long msk = 0;
        unsigned b4 = 0;
        #pragma unroll
        for (int r = 0; r < 4; ++r) b4 |= (c0[r] >= thr ? 1u : 0u) << r;
        msk |= (unsigned long long)b4 << (0 * 16 + rowbase);
        b4 = 0;
        #pragma unroll
        for (int r = 0; r < 4; ++r) b4 |= (c1[r] >= thr ? 1u : 0u) << r;
        msk |= (unsigned long long)b4 << (1 * 16 + rowbase);
        b4 = 0;
        #pragma unroll
        for (int r = 0; r < 4; ++r) b4 |= (c2[r] >= thr ? 1u : 0u) << r;
        msk |= (unsigned long long)b4 << (2 * 16 + rowbase);
        b4 = 0;
        #pragma unroll
        for (int r = 0; r < 4; ++r) b4 |= (c3[r] >= thr ? 1u : 0u) << r;
        msk |= (unsigned long long)b4 << (3 * 16 + rowbase);

        msk |= __shfl_xor(msk, 16);
        msk |= __shfl_xor(msk, 32);
        if (l < 16) {
            wavemax[wv][g16 * 16 + l] = mm;
            cmask[wv][g16 * 16 + l] = msk;
        }
    }
    __syncthreads();

    // ---- resolution: singleton inline; multi -> flat pair list ----
    if (tid < 128) {
        const int tok = tid;
        float gm = wavemax[0][tok];
        #pragma unroll
        for (int w = 1; w < 8; ++w) gm = fmaxf(gm, wavemax[w][tok]);
        const float thr = gm - marginArr[tok];
        int cnt = 0;
        int bk = -1;
        #pragma unroll
        for (int w = 0; w < 8; ++w) {
            if (wavemax[w][tok] >= thr) {
                unsigned long long mmm = cmask[w][tok];
                cnt += __popcll(mmm);
                if (mmm) bk = w * 64 + __builtin_ctzll(mmm);
            }
        }
        if (cnt == 1) {
            bkArr[tok] = bk;                // certified exact argmin
        } else {
            #pragma unroll
            for (int w = 0; w < 8; ++w) {
                if (wavemax[w][tok] < thr) continue;
                unsigned long long mmm = cmask[w][tok];
                while (mmm) {
                    const int bit = __builtin_ctzll(mmm); mmm &= mmm - 1;
                    const int k = w * 64 + bit;
                    const int idx = atomicAdd(&pcnt, 1);
                    if (idx < 1024) {
                        pairs[idx] = ((unsigned)tok << 16) | (unsigned)k;
                    } else {
                        // overflow fallback (statistically never): inline fp64
                        const float* xc = x + (size_t)b * 262144 + p0 + tok;
                        const float* wr = W + k * 64;
                        double acc = 0.0;
                        #pragma unroll 1
                        for (int d = 0; d < 64; ++d) {
                            double dl = (double)xc[(size_t)d * HW_] - (double)wr[d];
                            acc = fma(dl, dl, acc);
                        }
                        unsigned long long key =
                            (__double_as_longlong(acc) & ~1023ull) | (unsigned long long)k;
                        atomicMin(&bestKey[tok], key);
                    }
                }
            }
        }
    }
    __syncthreads();

    // ---- pair-parallel exact fp64 refine: one lane per (tok,k) pair ----
    {
        const int nP = min(pcnt, 1024);
        for (int i = tid; i < nP; i += 512) {
            const unsigned pr = pairs[i];
            const int tok = pr >> 16;
            const int k = pr & 0xffff;
            const float* xc = x + (size_t)b * 262144 + p0 + tok;
            const float* wr = W + k * 64;
            double acc = 0.0;
            #pragma unroll
            for (int d = 0; d < 64; ++d) {
                double dl = (double)xc[(size_t)d * HW_] - (double)wr[d];
                acc = fma(dl, dl, acc);
            }
            unsigned long long key =
                (__double_as_longlong(acc) & ~1023ull) | (unsigned long long)k;
            atomicMin(&bestKey[tok], key);
        }
    }
    __syncthreads();
    if (tid < 128 && bestKey[tid] != ~0ull)
        bkArr[tid] = (int)(bestKey[tid] & 1023ull);
    __syncthreads();

    // ---- epilogue: gather W rows (L2-hot), coalesced NCHW store ----
    {
        const int pp = tid & 127;            // token
        const int dq = tid >> 7;             // dim quarter 0..3
        const int kk = bkArr[pp];
        const float* wr = W + kk * 64 + dq * 16;
        float* ob = out + (size_t)b * 262144 + p0 + pp;
        #pragma unroll
        for (int j = 0; j < 4; ++j) {
            f32x4 v = *(const f32x4*)(wr + j * 4);
            ob[(size_t)(dq * 16 + j * 4 + 0) * HW_] = v[0];
            ob[(size_t)(dq * 16 + j * 4 + 1) * HW_] = v[1];
            ob[(size_t)(dq * 16 + j * 4 + 2) * HW_] = v[2];
            ob[(size_t)(dq * 16 + j * 4 + 3) * HW_] = v[3];
        }
    }
}

extern "C" void kernel_launch(void* const* d_in, const int* in_sizes, int n_in,
                              void* d_out, int out_size, void* d_ws, size_t ws_size,
                              hipStream_t stream) {
    const float* x = (const float*)d_in[0];
    const float* W = (const float*)d_in[1];
    unsigned short* Wb = (unsigned short*)d_ws;              // 64 KiB image
    float* nh = (float*)((char*)d_ws + 65536);               // 512 f32
    vq_prep<<<512, 64, 0, stream>>>(W, Wb, nh);
    vq_main<<<1024, 512, 0, stream>>>(x, W, Wb, nh, (float*)d_out);
}